// Round 21
// baseline (139.875 us; speedup 1.0000x reference)
//
#include <hip/hip_runtime.h>

#define GRID_D 64
#define NN (GRID_D * GRID_D)   // 4096 nodes per image
#define H 64
#define C_IN 12
#define B_SZ 128
#define LN_EPS 1e-5f

typedef _Float16 f16x8 __attribute__((ext_vector_type(8)));
typedef _Float16 f16x4 __attribute__((ext_vector_type(4)));
typedef float    f32x4 __attribute__((ext_vector_type(4)));

#define AS1 __attribute__((address_space(1)))
#define AS3 __attribute__((address_space(3)))

// ---------------------------------------------------------------------------
// Kernel 1: input projection  h0[b,n,j] = sum_c x[b,c,n]*w_in[c,j] + b_in[j]
// Blocks 0..95 additionally transpose Ws/Wn to f16 (folded k_prep).
// ---------------------------------------------------------------------------
__global__ __launch_bounds__(256) void k_inproj(
    const float* __restrict__ x, const float* __restrict__ w_in,
    const float* __restrict__ b_in, _Float16* __restrict__ h,
    const float* __restrict__ ws_, const float* __restrict__ wn_,
    _Float16* __restrict__ wt)
{
    int bid = blockIdx.x;            // b*64 + r
    int b = bid >> 6, r = bid & 63;
    int tid = threadIdx.x;

    // folded weight prep: wt[l][g][j][k] = W[l,g][k][j]
    int pi = bid * 256 + tid;
    if (pi < 3 * 2 * 4096) {
        int l = pi >> 13, g = (pi >> 12) & 1, j = (pi >> 6) & 63, k = pi & 63;
        const float* W = (g ? wn_ : ws_) + l * 4096;
        wt[pi] = (_Float16)W[k * 64 + j];
    }

    __shared__ float xs[C_IN][GRID_D];
    __shared__ float ws[C_IN][H];
    const float* xb = x + (size_t)b * C_IN * NN + (size_t)r * GRID_D;
    for (int idx = tid; idx < C_IN * GRID_D; idx += 256) {
        int c = idx >> 6, n = idx & 63;
        xs[c][n] = xb[(size_t)c * NN + n];
        ws[c][n] = w_in[idx];
    }
    __syncthreads();
    int n = tid >> 2;                // node 0..63
    int j0 = (tid & 3) * 16;         // 16-feat group
    float acc[16];
    #pragma unroll
    for (int t = 0; t < 16; ++t) acc[t] = b_in[j0 + t];
    #pragma unroll
    for (int c = 0; c < C_IN; ++c) {
        float xv = xs[c][n];
        #pragma unroll
        for (int t = 0; t < 16; ++t) acc[t] += xv * ws[c][j0 + t];
    }
    _Float16* hp = h + (size_t)(b * NN + r * GRID_D + n) * H + j0;
    f16x8 o0, o1;
    #pragma unroll
    for (int t = 0; t < 8; ++t) { o0[t] = (_Float16)acc[t]; o1[t] = (_Float16)acc[8 + t]; }
    *(f16x8*)hp = o0;
    *(f16x8*)(hp + 8) = o1;
}

// stage one grid row (64 nodes x 64 f16 = 8KB) into ring0 slot; linear dest,
// pre-swizzled per-lane global source (rule 21). Waves 0..7, one gload each.
__device__ __forceinline__ void stage_row(
    const _Float16* hb, int grow, _Float16* slot, int wv, int ln)
{
    const _Float16* src = hb
        + (((size_t)(grow * GRID_D + wv * 8 + (ln >> 3))) << 6)
        + (((ln & 7) ^ (ln >> 3)) << 3);
    _Float16* dst = slot + wv * 512;
    __builtin_amdgcn_global_load_lds((const AS1 void*)src, (AS3 void*)dst, 16, 0, 0);
}

// ---------------------------------------------------------------------------
// Kernel 2: FUSED 3 layers + head (R20 structure + LN-param hoist).
// Block = 768 thr (12 waves) owns 32 output rows of one image (grid 256 =
// 1 block/CU). Step s: stage h0[p0] async into ring0 (waves 0-7); waves 0-3:
// h1[p0-2] (ring0->ring1); waves 4-7: h2[p0-4] (ring1->ring2); waves 8-11:
// h3[p0-6]+head -> logits. One barrier/step; mod-4 ring slots. Weights: 16
// f16x8/lane in VGPRs, pinned — stable ONLY at block=768 + min-waves=3.
// R20 additions kept: zero-slot boundary handling, conv-bias hoist, setprio.
// NEW vs R20: LN gamma/beta quads (lgq/lbq, loop-invariant) hoisted to 8
// f32x4 registers — removes 8 ds_read_b128 per step per wave (~40% of
// epilogue LDS ops). VGPR ~116 stays under the 128 granule (pins + 16-wave
// ceiling preserved); w_head quads stay in LDS (hoisting would cross 128).
// ---------------------------------------------------------------------------
__global__ __launch_bounds__(768, 3) void k_fused(
    const _Float16* __restrict__ h0, float* __restrict__ logits,
    const _Float16* __restrict__ wtb,      // [3][2][64][64] transposed f16
    const float* __restrict__ cb, const float* __restrict__ lg,
    const float* __restrict__ lb,
    const float* __restrict__ w_head, const float* __restrict__ b_head)
{
    __shared__ _Float16 ring[3][4][4096];  // 96 KB
    __shared__ _Float16 zbuf[4096];        // 8 KB of zeros (boundary reads)
    __shared__ float    pl[640];           // cb|lg|lb per layer (3x192) + wh(64)

    int tid = threadIdx.x, ln = tid & 63, wv = tid >> 6;
    int bid = blockIdx.x;
    int img = bid >> 1, chunk = bid & 1;
    int r0 = chunk << 5;                   // 32 output rows
    const _Float16* hb = h0 + ((size_t)img << 18);

    int grp = wv >> 2;                     // 0,1,2 = layer-1,2,3
    int ct  = wv & 3;                      // col tile
    int lrow = ln & 15, kgrp = ln >> 4;
    int col = ct * 16 + lrow;
    int cs = col & 7;                      // == lrow & 7
    int kq = kgrp * 4;
    bool cl = (col > 0), cr = (col < 63);

    // ---- weights for my group's layer: 16 frags = 64 VGPR, pinned ----
    const _Float16* wg = wtb + grp * 8192;
    f16x8 wsf[2][4], wnf[2][4];
    #pragma unroll
    for (int ks = 0; ks < 2; ++ks) {
        int k0 = ks * 32 + kq * 2;         // ks*32 + kgrp*8
        #pragma unroll
        for (int ft = 0; ft < 4; ++ft) {
            int j = ft * 16 + lrow;
            wsf[ks][ft] = *(const f16x8*)(wg + (j << 6) + k0);
            wnf[ks][ft] = *(const f16x8*)(wg + ((64 + j) << 6) + k0);
        }
    }
    #pragma unroll
    for (int ks = 0; ks < 2; ++ks)
        #pragma unroll
        for (int ft = 0; ft < 4; ++ft)
            asm volatile("" : "+v"(wsf[ks][ft]), "+v"(wnf[ks][ft]));

    // ---- params + zero slot to LDS ----
    if (tid < 576) {
        int l = tid / 192, r = tid % 192;
        pl[tid] = (r < 64) ? cb[l * 64 + r]
                : (r < 128) ? lg[l * 64 + r - 64] : lb[l * 64 + r - 128];
    } else if (tid < 640) {
        pl[tid] = w_head[tid - 576];
    }
    if (tid < 512) {
        f16x8 z = {};
        *(f16x8*)&zbuf[tid * 8] = z;
    }
    __syncthreads();                       // publish params + zbuf for hoists

    const float* myp = pl + grp * 192;
    float bh = b_head[0];

    // hoisted loop-invariant param quads (12 x f32x4 = 48 VGPR)
    f32x4 cbq[4], lgq[4], lbq[4];
    #pragma unroll
    for (int ft = 0; ft < 4; ++ft) {
        cbq[ft] = *(const f32x4*)&myp[ft * 16 + kq];
        lgq[ft] = *(const f32x4*)&myp[64 + ft * 16 + kq];
        lbq[ft] = *(const f32x4*)&myp[128 + ft * 16 + kq];
    }

    // loop-invariant neighbor column offsets (element units)
    int colo = col << 6;
    int cmo = cl ? (((col - 1) << 6)) : 0;
    int cpo = cr ? (((col + 1) << 6)) : 0;

    // stage/compute validity ranges (clipped to image)
    int lo0 = (r0 - 3 < 0) ? 0 : r0 - 3, hi0 = (r0 + 34 > 63) ? 63 : r0 + 34;
    int loC, hiC;
    if (grp == 0)      { loC = (r0 - 2 < 0) ? 0 : r0 - 2; hiC = (r0 + 33 > 63) ? 63 : r0 + 33; }
    else if (grp == 1) { loC = (r0 - 1 < 0) ? 0 : r0 - 1; hiC = (r0 + 32 > 63) ? 63 : r0 + 32; }
    else               { loC = r0;                         hiC = r0 + 31; }

    _Float16* rin  = &ring[grp][0][0];                 // group g reads ring[g]
    _Float16* rout = (grp < 2) ? &ring[grp + 1][0][0] : nullptr;

    #pragma unroll 1
    for (int s = 0; s <= 40; ++s) {
        int p0 = r0 - 3 + s;
        if (wv < 8 && p0 >= lo0 && p0 <= hi0)
            stage_row(hb, p0, &ring[0][p0 & 3][0], wv, ln);

        int pr = p0 - 2 * grp - 2;                     // my group's row this step
        if (pr >= loC && pr <= hiC) {
            const _Float16* rc = rin + ((pr & 3) << 12);
            const _Float16* ruE = (pr > 0)  ? rin + (((pr - 1) & 3) << 12) : zbuf;
            const _Float16* rdE = (pr < 63) ? rin + (((pr + 1) & 3) << 12) : zbuf;
            _Float16 hinv = (_Float16)(1.0f / (float)((pr > 0) + (pr < 63) + cl + cr));

            f32x4 acc[4];
            #pragma unroll
            for (int ft = 0; ft < 4; ++ft) acc[ft] = (f32x4){0.f, 0.f, 0.f, 0.f};

            // phase 1: Ws^T @ self^T
            __builtin_amdgcn_s_setprio(1);
            #pragma unroll
            for (int ks = 0; ks < 2; ++ks) {
                int sl = ((ks * 4 + kgrp) ^ cs) << 3;
                f16x8 a = *(const f16x8*)(rc + colo + sl);
                #pragma unroll
                for (int ft = 0; ft < 4; ++ft)
                    acc[ft] = __builtin_amdgcn_mfma_f32_16x16x32_f16(wsf[ks][ft], a, acc[ft], 0, 0, 0);
            }

            // phase 2: Wn^T @ agg^T (zero-slot boundary reads)
            #pragma unroll
            for (int ks = 0; ks < 2; ++ks) {
                int c8 = ks * 4 + kgrp;
                int sl = (c8 ^ cs) << 3;
                f16x8 u = *(const f16x8*)(ruE + colo + sl);
                f16x8 d = *(const f16x8*)(rdE + colo + sl);
                const _Float16* lp = cl ? (rc + cmo + ((c8 ^ ((col - 1) & 7)) << 3)) : zbuf;
                const _Float16* rp = cr ? (rc + cpo + ((c8 ^ ((col + 1) & 7)) << 3)) : zbuf;
                f16x8 lv = *(const f16x8*)lp;
                f16x8 rv = *(const f16x8*)rp;
                f16x8 sm = (lv + rv) + (u + d);
                f16x8 g;
                #pragma unroll
                for (int e = 0; e < 8; ++e) g[e] = sm[e] * hinv;
                #pragma unroll
                for (int ft = 0; ft < 4; ++ft)
                    acc[ft] = __builtin_amdgcn_mfma_f32_16x16x32_f16(wnf[ks][ft], g, acc[ft], 0, 0, 0);
            }
            __builtin_amdgcn_s_setprio(0);

            // epilogue: +bias, LN, residual+ReLU -> ring or logits
            float s1 = 0.f, s2 = 0.f;
            #pragma unroll
            for (int ft = 0; ft < 4; ++ft) {
                acc[ft] += cbq[ft];
                #pragma unroll
                for (int t = 0; t < 4; ++t) { float xv = acc[ft][t]; s1 += xv; s2 += xv * xv; }
            }
            s1 += __shfl_xor(s1, 16); s1 += __shfl_xor(s1, 32);
            s2 += __shfl_xor(s2, 16); s2 += __shfl_xor(s2, 32);
            float mu   = s1 * (1.0f / H);
            float var  = s2 * (1.0f / H) - mu * mu;
            float rstd = rsqrtf(var + LN_EPS);

            const _Float16* res = rc + colo;
            if (grp < 2) {
                _Float16* outp = rout + ((pr & 3) << 12) + colo;
                #pragma unroll
                for (int ft = 0; ft < 4; ++ft) {
                    int slot = (ft * 2 + (kgrp >> 1)) ^ cs;
                    f16x4 rq = *(const f16x4*)(res + (slot << 3) + (kgrp & 1) * 4);
                    f16x4 oq;
                    #pragma unroll
                    for (int t = 0; t < 4; ++t) {
                        float o = (float)rq[t]
                                + fmaxf((acc[ft][t] - mu) * rstd * lgq[ft][t] + lbq[ft][t], 0.f);
                        oq[t] = (_Float16)o;
                    }
                    *(f16x4*)(outp + (slot << 3) + (kgrp & 1) * 4) = oq;
                }
            } else {
                float part = 0.f;
                #pragma unroll
                for (int ft = 0; ft < 4; ++ft) {
                    f32x4 whq = *(const f32x4*)&pl[576 + ft * 16 + kq];
                    int slot = (ft * 2 + (kgrp >> 1)) ^ cs;
                    f16x4 rq = *(const f16x4*)(res + (slot << 3) + (kgrp & 1) * 4);
                    #pragma unroll
                    for (int t = 0; t < 4; ++t) {
                        float o = (float)rq[t]
                                + fmaxf((acc[ft][t] - mu) * rstd * lgq[ft][t] + lbq[ft][t], 0.f);
                        part += o * whq[t];
                    }
                }
                part += __shfl_xor(part, 16);
                part += __shfl_xor(part, 32);
                if (kgrp == 0)
                    logits[(size_t)img * NN + pr * GRID_D + col] = part + bh;
            }
        }
        __syncthreads();   // lands stage (vmcnt drain) + publishes ring writes
    }
}

// ---------------------------------------------------------------------------
extern "C" void kernel_launch(void* const* d_in, const int* in_sizes, int n_in,
                              void* d_out, int out_size, void* d_ws, size_t ws_size,
                              hipStream_t stream) {
    const float* x      = (const float*)d_in[0];
    // d_in[1] edge_index: fixed grid 4-neighborhood -> computed as stencil, unused
    const float* w_in   = (const float*)d_in[2];
    const float* b_in   = (const float*)d_in[3];
    const float* w_self = (const float*)d_in[4];
    const float* w_neigh= (const float*)d_in[5];
    const float* conv_b = (const float*)d_in[6];
    const float* ln_g   = (const float*)d_in[7];
    const float* ln_b   = (const float*)d_in[8];
    const float* w_head = (const float*)d_in[9];
    const float* b_head = (const float*)d_in[10];
    float* out = (float*)d_out;

    char* base = (char*)d_ws;
    const size_t HBYTES = (size_t)B_SZ * NN * H * sizeof(_Float16);   // 64 MiB
    _Float16* h_a = (_Float16*)base;
    _Float16* wtb = (_Float16*)(base + HBYTES);                       // 48 KiB

    k_inproj<<<B_SZ * GRID_D, 256, 0, stream>>>(
        x, w_in, b_in, h_a, w_self, w_neigh, wtb);
    k_fused<<<B_SZ * 2, 768, 0, stream>>>(
        h_a, out, wtb, conv_b, ln_g, ln_b, w_head, b_head);
}

// Round 22
// 104.228 us; speedup vs baseline: 1.3420x; 1.3420x over previous
//
#include <hip/hip_runtime.h>

#define GRID_D 64
#define NN (GRID_D * GRID_D)   // 4096 nodes per image
#define H 64
#define C_IN 12
#define B_SZ 128
#define LN_EPS 1e-5f

typedef _Float16 f16x8 __attribute__((ext_vector_type(8)));
typedef _Float16 f16x4 __attribute__((ext_vector_type(4)));
typedef float    f32x4 __attribute__((ext_vector_type(4)));

#define AS1 __attribute__((address_space(1)))
#define AS3 __attribute__((address_space(3)))

// ---------------------------------------------------------------------------
// Kernel 1: input projection  h0[b,n,j] = sum_c x[b,c,n]*w_in[c,j] + b_in[j]
// Blocks 0..95 additionally transpose Ws/Wn to f16 (folded k_prep).
// ---------------------------------------------------------------------------
__global__ __launch_bounds__(256) void k_inproj(
    const float* __restrict__ x, const float* __restrict__ w_in,
    const float* __restrict__ b_in, _Float16* __restrict__ h,
    const float* __restrict__ ws_, const float* __restrict__ wn_,
    _Float16* __restrict__ wt)
{
    int bid = blockIdx.x;            // b*64 + r
    int b = bid >> 6, r = bid & 63;
    int tid = threadIdx.x;

    // folded weight prep: wt[l][g][j][k] = W[l,g][k][j]
    int pi = bid * 256 + tid;
    if (pi < 3 * 2 * 4096) {
        int l = pi >> 13, g = (pi >> 12) & 1, j = (pi >> 6) & 63, k = pi & 63;
        const float* W = (g ? wn_ : ws_) + l * 4096;
        wt[pi] = (_Float16)W[k * 64 + j];
    }

    __shared__ float xs[C_IN][GRID_D];
    __shared__ float ws[C_IN][H];
    const float* xb = x + (size_t)b * C_IN * NN + (size_t)r * GRID_D;
    for (int idx = tid; idx < C_IN * GRID_D; idx += 256) {
        int c = idx >> 6, n = idx & 63;
        xs[c][n] = xb[(size_t)c * NN + n];
        ws[c][n] = w_in[idx];
    }
    __syncthreads();
    int n = tid >> 2;                // node 0..63
    int j0 = (tid & 3) * 16;         // 16-feat group
    float acc[16];
    #pragma unroll
    for (int t = 0; t < 16; ++t) acc[t] = b_in[j0 + t];
    #pragma unroll
    for (int c = 0; c < C_IN; ++c) {
        float xv = xs[c][n];
        #pragma unroll
        for (int t = 0; t < 16; ++t) acc[t] += xv * ws[c][j0 + t];
    }
    _Float16* hp = h + (size_t)(b * NN + r * GRID_D + n) * H + j0;
    f16x8 o0, o1;
    #pragma unroll
    for (int t = 0; t < 8; ++t) { o0[t] = (_Float16)acc[t]; o1[t] = (_Float16)acc[8 + t]; }
    *(f16x8*)hp = o0;
    *(f16x8*)(hp + 8) = o1;
}

// stage one grid row (64 nodes x 64 f16 = 8KB) into ring0 slot; linear dest,
// pre-swizzled per-lane global source (rule 21). Waves 0..7, one gload each.
__device__ __forceinline__ void stage_row(
    const _Float16* hb, int grow, _Float16* slot, int wv, int ln)
{
    const _Float16* src = hb
        + (((size_t)(grow * GRID_D + wv * 8 + (ln >> 3))) << 6)
        + (((ln & 7) ^ (ln >> 3)) << 3);
    _Float16* dst = slot + wv * 512;
    __builtin_amdgcn_global_load_lds((const AS1 void*)src, (AS3 void*)dst, 16, 0, 0);
}

// ---------------------------------------------------------------------------
// Kernel 2: FUSED 3 layers + head (R20 configuration — measured best,
// 104.3 us total / 94.4 us kernel, VGPR 84 with weight pins held).
// Block = 768 thr (12 waves) owns 32 output rows of one image (grid 256 =
// 1 block/CU). Step s: stage h0[p0] async into ring0 (waves 0-7); waves 0-3:
// h1[p0-2] (ring0->ring1); waves 4-7: h2[p0-4] (ring1->ring2); waves 8-11:
// h3[p0-6]+head -> logits. One barrier/step; mod-4 ring slots. Weights: 16
// f16x8/lane in VGPRs, pinned — stable ONLY at block=768 + min-waves=3.
// Zero-slot boundary handling (wave-uniform row-pointer selects + per-lane
// col-address selects into an 8KB zeroed LDS row); conv-bias quads hoisted
// (register-neutral equilibrium — R21 showed further hoisting breaks the
// allocator's pin equilibrium); setprio(1) around MFMA.
// ---------------------------------------------------------------------------
__global__ __launch_bounds__(768, 3) void k_fused(
    const _Float16* __restrict__ h0, float* __restrict__ logits,
    const _Float16* __restrict__ wtb,      // [3][2][64][64] transposed f16
    const float* __restrict__ cb, const float* __restrict__ lg,
    const float* __restrict__ lb,
    const float* __restrict__ w_head, const float* __restrict__ b_head)
{
    __shared__ _Float16 ring[3][4][4096];  // 96 KB
    __shared__ _Float16 zbuf[4096];        // 8 KB of zeros (boundary reads)
    __shared__ float    pl[640];           // cb|lg|lb per layer (3x192) + wh(64)

    int tid = threadIdx.x, ln = tid & 63, wv = tid >> 6;
    int bid = blockIdx.x;
    int img = bid >> 1, chunk = bid & 1;
    int r0 = chunk << 5;                   // 32 output rows
    const _Float16* hb = h0 + ((size_t)img << 18);

    int grp = wv >> 2;                     // 0,1,2 = layer-1,2,3
    int ct  = wv & 3;                      // col tile
    int lrow = ln & 15, kgrp = ln >> 4;
    int col = ct * 16 + lrow;
    int cs = col & 7;                      // == lrow & 7
    int kq = kgrp * 4;
    bool cl = (col > 0), cr = (col < 63);

    // ---- weights for my group's layer: 16 frags = 64 VGPR, pinned ----
    const _Float16* wg = wtb + grp * 8192;
    f16x8 wsf[2][4], wnf[2][4];
    #pragma unroll
    for (int ks = 0; ks < 2; ++ks) {
        int k0 = ks * 32 + kq * 2;         // ks*32 + kgrp*8
        #pragma unroll
        for (int ft = 0; ft < 4; ++ft) {
            int j = ft * 16 + lrow;
            wsf[ks][ft] = *(const f16x8*)(wg + (j << 6) + k0);
            wnf[ks][ft] = *(const f16x8*)(wg + ((64 + j) << 6) + k0);
        }
    }
    #pragma unroll
    for (int ks = 0; ks < 2; ++ks)
        #pragma unroll
        for (int ft = 0; ft < 4; ++ft)
            asm volatile("" : "+v"(wsf[ks][ft]), "+v"(wnf[ks][ft]));

    // ---- params + zero slot to LDS ----
    if (tid < 576) {
        int l = tid / 192, r = tid % 192;
        pl[tid] = (r < 64) ? cb[l * 64 + r]
                : (r < 128) ? lg[l * 64 + r - 64] : lb[l * 64 + r - 128];
    } else if (tid < 640) {
        pl[tid] = w_head[tid - 576];
    }
    if (tid < 512) {
        f16x8 z = {};
        *(f16x8*)&zbuf[tid * 8] = z;
    }
    __syncthreads();                       // publish params + zbuf for hoists

    const float* myp = pl + grp * 192;
    float bh = b_head[0];

    // hoisted loop-invariant conv-bias quads (4 x f32x4 = 16 VGPR)
    f32x4 cbq[4];
    #pragma unroll
    for (int ft = 0; ft < 4; ++ft) cbq[ft] = *(const f32x4*)&myp[ft * 16 + kq];

    // loop-invariant neighbor column offsets (element units)
    int colo = col << 6;
    int cmo = cl ? (((col - 1) << 6)) : 0;
    int cpo = cr ? (((col + 1) << 6)) : 0;

    // stage/compute validity ranges (clipped to image)
    int lo0 = (r0 - 3 < 0) ? 0 : r0 - 3, hi0 = (r0 + 34 > 63) ? 63 : r0 + 34;
    int loC, hiC;
    if (grp == 0)      { loC = (r0 - 2 < 0) ? 0 : r0 - 2; hiC = (r0 + 33 > 63) ? 63 : r0 + 33; }
    else if (grp == 1) { loC = (r0 - 1 < 0) ? 0 : r0 - 1; hiC = (r0 + 32 > 63) ? 63 : r0 + 32; }
    else               { loC = r0;                         hiC = r0 + 31; }

    _Float16* rin  = &ring[grp][0][0];                 // group g reads ring[g]
    _Float16* rout = (grp < 2) ? &ring[grp + 1][0][0] : nullptr;

    #pragma unroll 1
    for (int s = 0; s <= 40; ++s) {
        int p0 = r0 - 3 + s;
        if (wv < 8 && p0 >= lo0 && p0 <= hi0)
            stage_row(hb, p0, &ring[0][p0 & 3][0], wv, ln);

        int pr = p0 - 2 * grp - 2;                     // my group's row this step
        if (pr >= loC && pr <= hiC) {
            const _Float16* rc = rin + ((pr & 3) << 12);
            const _Float16* ruE = (pr > 0)  ? rin + (((pr - 1) & 3) << 12) : zbuf;
            const _Float16* rdE = (pr < 63) ? rin + (((pr + 1) & 3) << 12) : zbuf;
            _Float16 hinv = (_Float16)(1.0f / (float)((pr > 0) + (pr < 63) + cl + cr));

            f32x4 acc[4];
            #pragma unroll
            for (int ft = 0; ft < 4; ++ft) acc[ft] = (f32x4){0.f, 0.f, 0.f, 0.f};

            // phase 1: Ws^T @ self^T
            __builtin_amdgcn_s_setprio(1);
            #pragma unroll
            for (int ks = 0; ks < 2; ++ks) {
                int sl = ((ks * 4 + kgrp) ^ cs) << 3;
                f16x8 a = *(const f16x8*)(rc + colo + sl);
                #pragma unroll
                for (int ft = 0; ft < 4; ++ft)
                    acc[ft] = __builtin_amdgcn_mfma_f32_16x16x32_f16(wsf[ks][ft], a, acc[ft], 0, 0, 0);
            }

            // phase 2: Wn^T @ agg^T (zero-slot boundary reads)
            #pragma unroll
            for (int ks = 0; ks < 2; ++ks) {
                int c8 = ks * 4 + kgrp;
                int sl = (c8 ^ cs) << 3;
                f16x8 u = *(const f16x8*)(ruE + colo + sl);
                f16x8 d = *(const f16x8*)(rdE + colo + sl);
                const _Float16* lp = cl ? (rc + cmo + ((c8 ^ ((col - 1) & 7)) << 3)) : zbuf;
                const _Float16* rp = cr ? (rc + cpo + ((c8 ^ ((col + 1) & 7)) << 3)) : zbuf;
                f16x8 lv = *(const f16x8*)lp;
                f16x8 rv = *(const f16x8*)rp;
                f16x8 sm = (lv + rv) + (u + d);
                f16x8 g;
                #pragma unroll
                for (int e = 0; e < 8; ++e) g[e] = sm[e] * hinv;
                #pragma unroll
                for (int ft = 0; ft < 4; ++ft)
                    acc[ft] = __builtin_amdgcn_mfma_f32_16x16x32_f16(wnf[ks][ft], g, acc[ft], 0, 0, 0);
            }
            __builtin_amdgcn_s_setprio(0);

            // epilogue: +bias, LN, residual+ReLU -> ring or logits
            float s1 = 0.f, s2 = 0.f;
            #pragma unroll
            for (int ft = 0; ft < 4; ++ft) {
                acc[ft] += cbq[ft];
                #pragma unroll
                for (int t = 0; t < 4; ++t) { float xv = acc[ft][t]; s1 += xv; s2 += xv * xv; }
            }
            s1 += __shfl_xor(s1, 16); s1 += __shfl_xor(s1, 32);
            s2 += __shfl_xor(s2, 16); s2 += __shfl_xor(s2, 32);
            float mu   = s1 * (1.0f / H);
            float var  = s2 * (1.0f / H) - mu * mu;
            float rstd = rsqrtf(var + LN_EPS);

            const _Float16* res = rc + colo;
            if (grp < 2) {
                _Float16* outp = rout + ((pr & 3) << 12) + colo;
                #pragma unroll
                for (int ft = 0; ft < 4; ++ft) {
                    f32x4 lgq = *(const f32x4*)&myp[64 + ft * 16 + kq];
                    f32x4 lbq = *(const f32x4*)&myp[128 + ft * 16 + kq];
                    int slot = (ft * 2 + (kgrp >> 1)) ^ cs;
                    f16x4 rq = *(const f16x4*)(res + (slot << 3) + (kgrp & 1) * 4);
                    f16x4 oq;
                    #pragma unroll
                    for (int t = 0; t < 4; ++t) {
                        float o = (float)rq[t]
                                + fmaxf((acc[ft][t] - mu) * rstd * lgq[t] + lbq[t], 0.f);
                        oq[t] = (_Float16)o;
                    }
                    *(f16x4*)(outp + (slot << 3) + (kgrp & 1) * 4) = oq;
                }
            } else {
                float part = 0.f;
                #pragma unroll
                for (int ft = 0; ft < 4; ++ft) {
                    f32x4 lgq = *(const f32x4*)&myp[64 + ft * 16 + kq];
                    f32x4 lbq = *(const f32x4*)&myp[128 + ft * 16 + kq];
                    f32x4 whq = *(const f32x4*)&pl[576 + ft * 16 + kq];
                    int slot = (ft * 2 + (kgrp >> 1)) ^ cs;
                    f16x4 rq = *(const f16x4*)(res + (slot << 3) + (kgrp & 1) * 4);
                    #pragma unroll
                    for (int t = 0; t < 4; ++t) {
                        float o = (float)rq[t]
                                + fmaxf((acc[ft][t] - mu) * rstd * lgq[t] + lbq[t], 0.f);
                        part += o * whq[t];
                    }
                }
                part += __shfl_xor(part, 16);
                part += __shfl_xor(part, 32);
                if (kgrp == 0)
                    logits[(size_t)img * NN + pr * GRID_D + col] = part + bh;
            }
        }
        __syncthreads();   // lands stage (vmcnt drain) + publishes ring writes
    }
}

// ---------------------------------------------------------------------------
extern "C" void kernel_launch(void* const* d_in, const int* in_sizes, int n_in,
                              void* d_out, int out_size, void* d_ws, size_t ws_size,
                              hipStream_t stream) {
    const float* x      = (const float*)d_in[0];
    // d_in[1] edge_index: fixed grid 4-neighborhood -> computed as stencil, unused
    const float* w_in   = (const float*)d_in[2];
    const float* b_in   = (const float*)d_in[3];
    const float* w_self = (const float*)d_in[4];
    const float* w_neigh= (const float*)d_in[5];
    const float* conv_b = (const float*)d_in[6];
    const float* ln_g   = (const float*)d_in[7];
    const float* ln_b   = (const float*)d_in[8];
    const float* w_head = (const float*)d_in[9];
    const float* b_head = (const float*)d_in[10];
    float* out = (float*)d_out;

    char* base = (char*)d_ws;
    const size_t HBYTES = (size_t)B_SZ * NN * H * sizeof(_Float16);   // 64 MiB
    _Float16* h_a = (_Float16*)base;
    _Float16* wtb = (_Float16*)(base + HBYTES);                       // 48 KiB

    k_inproj<<<B_SZ * GRID_D, 256, 0, stream>>>(
        x, w_in, b_in, h_a, w_self, w_neigh, wtb);
    k_fused<<<B_SZ * 2, 768, 0, stream>>>(
        h_a, out, wtb, conv_b, ln_g, ln_b, w_head, b_head);
}